// Round 5
// baseline (246.720 us; speedup 1.0000x reference)
//
#include <hip/hip_runtime.h>

// Dynamic grouped conv, fully fused single kernel.
//
// Factorization: the dynamic 3x3 kernel is broadcast across the 8 input
// channels of each group, so
//   out[b,oc] = conv3x3( S[b,g], w[b,oc] ),  S[b,g] = sum of the group's 8 chans.
//
// R5..R9: fuse the former two-kernel split (group-sum -> d_ws -> conv) into
// ONE kernel: each block stages the group-summed 34x66 tile of S directly into
// LDS (8-channel float4 gather-sum), then applies the 8 dynamic 3x3 filters.
//   - removes the 33.6 MB S round-trip through HBM (302 -> ~281 MB total)
//   - removes one dispatch + the A->B launch/drain bubble
//   - dynamic weights stored LDS-padded to 12 floats/oc so each oc's taps read
//     as b128+b128+b32 instead of 9x unaligned ds_read_b32
//   (R9: dropped __builtin_nontemporal_store — the only never-run-on-HW
//    construct — after 3 consecutive container failures; plain float4 stores.)
// Tile: 32 rows x 64 cols, 512 threads, 4 px/thread, grid 8b*8g*8ty*4tx = 2048.

#define LDSW 68   // row stride in floats; rows 16B-aligned (68*4 = 272 = 17*16)
#define TH 32
#define TW 64

__device__ __forceinline__ int reflect1(int i, int n) {
  if (i < 0) i = -i;
  if (i >= n) i = 2 * n - 2 - i;
  return i;
}

__global__ __launch_bounds__(512) void dynconv_fused512(
    const float* __restrict__ x,     // [8,64,256,256]
    const float* __restrict__ rep,   // [8,32]
    const float* __restrict__ W,     // [576,32]
    float* __restrict__ out) {       // [8,64,256,256]
  const int tid = threadIdx.x;
  const int tx = blockIdx.x & 3;           // 4 tiles of 64 along x
  const int ty = (blockIdx.x >> 2) & 7;    // 8 tiles of 32 along y
  const int g  = (blockIdx.x >> 5) & 7;
  const int b  = blockIdx.x >> 8;

  __shared__ float s[(TH + 2) * LDSW];     // 34 x 68 = 9248 B
  __shared__ float wl[96];                 // 8 oc x 12 (9 taps padded to 12)

  // dynamic weights for this (b, g): 72 dots of length 32
  if (tid < 72) {
    const int oc  = tid / 9;
    const int tap = tid - oc * 9;
    const int row = g * 72 + tid;          // (g*8 + oc)*9 + tap
    const float* wr = W + (size_t)row * 32;
    const float* rb = rep + b * 32;
    float acc = 0.f;
#pragma unroll
    for (int j = 0; j < 32; ++j) acc += rb[j] * wr[j];
    wl[oc * 12 + tap] = (acc > 0.f) ? acc : 0.1f * acc;
  }

  // stage group-summed S tile: 34 rows x 16 float4 segs (544 slots), plus
  // halo cols at s[.,64] (right) / s[.,66] (left), 68 items.
  const int gx0 = tx * TW, gy0 = ty * TH;
  const float* xg = x + ((size_t)(b * 64 + g * 8)) * 65536;
  const float4* xg4 = (const float4*)xg;

  for (int t = tid; t < 34 * 16; t += 512) {
    const int row = t >> 4, seg = t & 15;
    const int yy = reflect1(gy0 + row - 1, 256);
    const float4* p = xg4 + (size_t)yy * 64 + (gx0 >> 2) + seg;
    float4 v0 = p[0 * 16384], v1 = p[1 * 16384], v2 = p[2 * 16384], v3 = p[3 * 16384];
    float4 v4 = p[4 * 16384], v5 = p[5 * 16384], v6 = p[6 * 16384], v7 = p[7 * 16384];
    float4 a;
    a.x = ((v0.x + v1.x) + (v2.x + v3.x)) + ((v4.x + v5.x) + (v6.x + v7.x));
    a.y = ((v0.y + v1.y) + (v2.y + v3.y)) + ((v4.y + v5.y) + (v6.y + v7.y));
    a.z = ((v0.z + v1.z) + (v2.z + v3.z)) + ((v4.z + v5.z) + (v6.z + v7.z));
    a.w = ((v0.w + v1.w) + (v2.w + v3.w)) + ((v4.w + v5.w) + (v6.w + v7.w));
    *(float4*)&s[row * LDSW + seg * 4] = a;
  }
  if (tid < 68) {
    const int row = tid >> 1, side = tid & 1;
    const int scol = side ? 64 : 66;       // right halo -> col 64, left -> col 66
    const int yy = reflect1(gy0 + row - 1, 256);
    const int xx = reflect1(gx0 + (side ? 64 : -1), 256);
    const float* p = xg + (size_t)yy * 256 + xx;
    float a = 0.f;
#pragma unroll
    for (int c = 0; c < 8; ++c) a += p[(size_t)c * 65536];
    s[row * LDSW + scol] = a;
  }
  __syncthreads();

  // compute: 4 pixels/thread, one pass; window cols cs-1 .. cs+4
  const int cs = (tid & 15) * 4;           // 0..60
  const int rr = tid >> 4;                 // 0..31

  float win[3][6];
#pragma unroll
  for (int dy = 0; dy < 3; ++dy) {
    const float* row = &s[(rr + dy) * LDSW];
    float4 a = *(const float4*)&row[cs];           // cols cs..cs+3 (16B aligned)
    float  r = row[cs + 4];                        // col cs+4 (cs=60 -> halo col 64)
    float  l = row[(cs == 0) ? 66 : cs - 1];       // col cs-1 (cs=0 -> halo col 66)
    win[dy][0] = l;   win[dy][1] = a.x; win[dy][2] = a.y;
    win[dy][3] = a.z; win[dy][4] = a.w; win[dy][5] = r;
  }

  const int y = gy0 + rr;
  float* ob = out + (((size_t)(b * 64 + g * 8) * 256 + y) * 256 + gx0 + cs);

#pragma unroll
  for (int oc = 0; oc < 8; ++oc) {
    const float* w = &wl[oc * 12];         // 16B-aligned: b128 + b128 + b32
    const float w00 = w[0], w01 = w[1], w02 = w[2];
    const float w10 = w[3], w11 = w[4], w12 = w[5];
    const float w20 = w[6], w21 = w[7], w22 = w[8];
    float4 o;
    o.x = w00 * win[0][0] + w01 * win[0][1] + w02 * win[0][2]
        + w10 * win[1][0] + w11 * win[1][1] + w12 * win[1][2]
        + w20 * win[2][0] + w21 * win[2][1] + w22 * win[2][2];
    o.y = w00 * win[0][1] + w01 * win[0][2] + w02 * win[0][3]
        + w10 * win[1][1] + w11 * win[1][2] + w12 * win[1][3]
        + w20 * win[2][1] + w21 * win[2][2] + w22 * win[2][3];
    o.z = w00 * win[0][2] + w01 * win[0][3] + w02 * win[0][4]
        + w10 * win[1][2] + w11 * win[1][3] + w12 * win[1][4]
        + w20 * win[2][2] + w21 * win[2][3] + w22 * win[2][4];
    o.w = w00 * win[0][3] + w01 * win[0][4] + w02 * win[0][5]
        + w10 * win[1][3] + w11 * win[1][4] + w12 * win[1][5]
        + w20 * win[2][3] + w21 * win[2][4] + w22 * win[2][5];
    *(float4*)(ob + (size_t)oc * 65536) = o;
  }
}

extern "C" void kernel_launch(void* const* d_in, const int* in_sizes, int n_in,
                              void* d_out, int out_size, void* d_ws, size_t ws_size,
                              hipStream_t stream) {
  const float* x   = (const float*)d_in[0];
  const float* rep = (const float*)d_in[1];
  const float* W   = (const float*)d_in[2];
  float* out = (float*)d_out;
  hipLaunchKernelGGL(dynconv_fused512, dim3(2048), dim3(512), 0, stream,
                     x, rep, W, out);
}

// Round 6
// 241.066 us; speedup vs baseline: 1.0235x; 1.0235x over previous
//
#include <hip/hip_runtime.h>

// Dynamic grouped conv, fused, FULL-WIDTH row tiles.
//
// Factorization: out[b,oc] = conv3x3( S[b,g], w[b,oc] ),
//   S[b,g] = sum of the group's 8 input channels (dynamic 3x3 kernel is
//   broadcast across the group's input channels).
//
// R10: R5's 64-wide tile ran at 3.05 TB/s (38% peak, VALUBusy 7.8%) — DRAM
// efficiency-bound: every wave touched 256B runs scattered over 4 rows x 8
// channel streams. This version uses 8-row x 256-col (full-width) tiles with
// 256 threads so ONE WAVE = ONE ROW:
//   - staging loads:  1KB contiguous per channel per load instruction
//   - output stores:  1KB contiguous per wave per oc
//   - x-halo columns eliminated (reflect = LDS index remap: -1->1, 256->254)
//   - cost: row halo 10/8 = +25% fetch (138 -> ~168 MB)
// LDS 10.6 KB, 256 thr -> 8 blocks/CU, 32 waves/CU. Grid 8b*8g*32ty = 2048.

#define LROW 260   // LDS row stride in floats (260*4 = 1040 B, 16B-aligned)
#define TH 8

__device__ __forceinline__ int reflect1(int i, int n) {
  if (i < 0) i = -i;
  if (i >= n) i = 2 * n - 2 - i;
  return i;
}

__global__ __launch_bounds__(256) void dynconv_rows(
    const float* __restrict__ x,     // [8,64,256,256]
    const float* __restrict__ rep,   // [8,32]
    const float* __restrict__ W,     // [576,32]
    float* __restrict__ out) {       // [8,64,256,256]
  const int tid = threadIdx.x;
  const int ty = blockIdx.x & 31;          // 32 tiles of 8 rows
  const int g  = (blockIdx.x >> 5) & 7;
  const int b  = blockIdx.x >> 8;

  __shared__ float s[(TH + 2) * LROW];     // 10 x 260 floats = 10400 B
  __shared__ float wl[96];                 // 8 oc x 12 (9 taps padded to 12)

  // dynamic weights for this (b, g): 72 dots of length 32
  if (tid < 72) {
    const int oc  = tid / 9;
    const int tap = tid - oc * 9;
    const int row = g * 72 + tid;          // (g*8 + oc)*9 + tap
    const float* wr = W + (size_t)row * 32;
    const float* rb = rep + b * 32;
    float acc = 0.f;
#pragma unroll
    for (int j = 0; j < 32; ++j) acc += rb[j] * wr[j];
    wl[oc * 12 + tap] = (acc > 0.f) ? acc : 0.1f * acc;
  }

  // stage group-summed S rows: 10 rows x 64 float4 segs = 640 items.
  // wave = one row per iteration -> 1KB contiguous per channel.
  const int gy0 = ty * TH;
  const float* xg = x + ((size_t)(b * 64 + g * 8)) * 65536;
  const float4* xg4 = (const float4*)xg;

#pragma unroll
  for (int it = 0; it < 3; ++it) {
    const int t = tid + it * 256;
    if (it < 2 || t < 640) {               // it=2 only for tid<128
      const int row = t >> 6, seg = t & 63;
      const int yy = reflect1(gy0 + row - 1, 256);
      const float4* p = xg4 + (size_t)yy * 64 + seg;
      float4 v0 = p[0 * 16384], v1 = p[1 * 16384], v2 = p[2 * 16384], v3 = p[3 * 16384];
      float4 v4 = p[4 * 16384], v5 = p[5 * 16384], v6 = p[6 * 16384], v7 = p[7 * 16384];
      float4 a;
      a.x = ((v0.x + v1.x) + (v2.x + v3.x)) + ((v4.x + v5.x) + (v6.x + v7.x));
      a.y = ((v0.y + v1.y) + (v2.y + v3.y)) + ((v4.y + v5.y) + (v6.y + v7.y));
      a.z = ((v0.z + v1.z) + (v2.z + v3.z)) + ((v4.z + v5.z) + (v6.z + v7.z));
      a.w = ((v0.w + v1.w) + (v2.w + v3.w)) + ((v4.w + v5.w) + (v6.w + v7.w));
      *(float4*)&s[row * LROW + seg * 4] = a;
    }
  }
  __syncthreads();

  // compute: wave = one row, 4 px/lane; rows r0 and r0+4.
  const int cs = (tid & 63) * 4;           // 0..252
  const int r0 = tid >> 6;                 // 0..3

#pragma unroll
  for (int it = 0; it < 2; ++it) {
    const int rr = r0 + it * 4;            // 0..7
    float win[3][6];
#pragma unroll
    for (int dy = 0; dy < 3; ++dy) {
      const float* row = &s[(rr + dy) * LROW];
      float4 a = *(const float4*)&row[cs];             // cols cs..cs+3
      float  r = row[(cs == 252) ? 254 : cs + 4];      // reflect 256 -> 254
      float  l = row[(cs == 0) ? 1 : cs - 1];          // reflect  -1 -> 1
      win[dy][0] = l;   win[dy][1] = a.x; win[dy][2] = a.y;
      win[dy][3] = a.z; win[dy][4] = a.w; win[dy][5] = r;
    }

    const int y = gy0 + rr;
    float* ob = out + (((size_t)(b * 64 + g * 8) * 256 + y) * 256 + cs);

#pragma unroll
    for (int oc = 0; oc < 8; ++oc) {
      const float* w = &wl[oc * 12];       // 16B-aligned: b128 + b128 + b32
      const float w00 = w[0], w01 = w[1], w02 = w[2];
      const float w10 = w[3], w11 = w[4], w12 = w[5];
      const float w20 = w[6], w21 = w[7], w22 = w[8];
      float4 o;
      o.x = w00 * win[0][0] + w01 * win[0][1] + w02 * win[0][2]
          + w10 * win[1][0] + w11 * win[1][1] + w12 * win[1][2]
          + w20 * win[2][0] + w21 * win[2][1] + w22 * win[2][2];
      o.y = w00 * win[0][1] + w01 * win[0][2] + w02 * win[0][3]
          + w10 * win[1][1] + w11 * win[1][2] + w12 * win[1][3]
          + w20 * win[2][1] + w21 * win[2][2] + w22 * win[2][3];
      o.z = w00 * win[0][2] + w01 * win[0][3] + w02 * win[0][4]
          + w10 * win[1][2] + w11 * win[1][3] + w12 * win[1][4]
          + w20 * win[2][2] + w21 * win[2][3] + w22 * win[2][4];
      o.w = w00 * win[0][3] + w01 * win[0][4] + w02 * win[0][5]
          + w10 * win[1][3] + w11 * win[1][4] + w12 * win[1][5]
          + w20 * win[2][3] + w21 * win[2][4] + w22 * win[2][5];
      *(float4*)(ob + (size_t)oc * 65536) = o;
    }
  }
}

extern "C" void kernel_launch(void* const* d_in, const int* in_sizes, int n_in,
                              void* d_out, int out_size, void* d_ws, size_t ws_size,
                              hipStream_t stream) {
  const float* x   = (const float*)d_in[0];
  const float* rep = (const float*)d_in[1];
  const float* W   = (const float*)d_in[2];
  float* out = (float*)d_out;
  hipLaunchKernelGGL(dynconv_rows, dim3(2048), dim3(256), 0, stream,
                     x, rep, W, out);
}

// Round 7
// 239.825 us; speedup vs baseline: 1.0288x; 1.0052x over previous
//
#include <hip/hip_runtime.h>

// Dynamic grouped conv, two-dispatch split (R11).
//
// Factorization: out[b,oc] = conv3x3( S[b,g], w[b,oc] ),
//   S[b,g] = sum of the group's 8 input channels.
//
// R6 post-mortem: the fused kernel is phase-convoy-bound (stage->barrier->
// compute lockstep; HBM 2.6 TB/s, VALU 7.8%, nothing saturated). Split into
// two single-phase pattern-pure dispatches:
//   A: S = group-sum. Pure float4 streaming, 134 MB R + 16.8 MB W (verified
//      ~5.8 TB/s pattern in R0).
//   B: conv on S. S (16.8 MB) is L2/L3-resident after A, so NO LDS staging,
//      NO barrier phase: each thread loads its 3x6 window of S straight from
//      cache (~3x redundancy = ~50 MB of cache traffic), 288 FMAs, then
//      8 oc-stores with one full 1KB row contiguous per wave -> B is a pure
//      write-stream kernel like the 6.8 TB/s fill.
// Fallback (ws too small): R6's fused full-width kernel (verified, 83.9 us).

__device__ __forceinline__ int reflect1(int i, int n) {
  if (i < 0) i = -i;
  if (i >= n) i = 2 * n - 2 - i;
  return i;
}

// ---------------- Kernel A: group-sum ----------------
__global__ __launch_bounds__(256) void gsum_kernel(
    const float* __restrict__ x,   // [8,64,256,256]
    float* __restrict__ S) {       // [8,8,256,256]
  const int i = blockIdx.x * 256 + threadIdx.x;   // float4 idx, 0..1048575
  const int plane = i >> 14;                      // b*8 + g
  const int off = i & 16383;
  const float4* p = (const float4*)x + (size_t)plane * 8 * 16384 + off;
  float4 a;
  {
    float4 v0 = p[0],         v1 = p[16384],     v2 = p[2 * 16384], v3 = p[3 * 16384];
    float4 v4 = p[4 * 16384], v5 = p[5 * 16384], v6 = p[6 * 16384], v7 = p[7 * 16384];
    a.x = ((v0.x + v1.x) + (v2.x + v3.x)) + ((v4.x + v5.x) + (v6.x + v7.x));
    a.y = ((v0.y + v1.y) + (v2.y + v3.y)) + ((v4.y + v5.y) + (v6.y + v7.y));
    a.z = ((v0.z + v1.z) + (v2.z + v3.z)) + ((v4.z + v5.z) + (v6.z + v7.z));
    a.w = ((v0.w + v1.w) + (v2.w + v3.w)) + ((v4.w + v5.w) + (v6.w + v7.w));
  }
  ((float4*)S)[i] = a;
}

// ---------------- Kernel B: conv3x3 on cache-resident S ----------------
// block = 256 thr = 4 waves; wave = one full 256-px row (4 px/lane).
// grid = 8b * 8g * 64 row-tiles = 4096.
__global__ __launch_bounds__(256) void conv_rows(
    const float* __restrict__ S,     // [8,8,256,256]
    const float* __restrict__ rep,   // [8,32]
    const float* __restrict__ W,     // [576,32]
    float* __restrict__ out) {       // [8,64,256,256]
  const int tid = threadIdx.x;
  const int rt = blockIdx.x & 63;          // 64 tiles of 4 rows
  const int g  = (blockIdx.x >> 6) & 7;
  const int b  = blockIdx.x >> 9;

  __shared__ float wl[96];                 // 8 oc x 12 (9 taps padded to 12)

  if (tid < 72) {
    const int oc  = tid / 9;
    const int tap = tid - oc * 9;
    const int row = g * 72 + tid;          // (g*8 + oc)*9 + tap
    const float* wr = W + (size_t)row * 32;
    const float* rb = rep + b * 32;
    float acc = 0.f;
#pragma unroll
    for (int j = 0; j < 32; ++j) acc += rb[j] * wr[j];
    wl[oc * 12 + tap] = (acc > 0.f) ? acc : 0.1f * acc;
  }
  __syncthreads();

  const int lane = tid & 63;
  const int wv   = tid >> 6;               // 0..3
  const int y    = rt * 4 + wv;            // 0..255
  const int cs   = lane * 4;               // 0..252

  const float* Sp = S + (size_t)(b * 8 + g) * 65536;
  const int ym = reflect1(y - 1, 256);
  const int yp = reflect1(y + 1, 256);
  const int cl = (cs == 0) ? 1 : cs - 1;       // reflect -1 -> 1
  const int cr = (cs == 252) ? 254 : cs + 4;   // reflect 256 -> 254

  float win[3][6];
  {
    const int rows[3] = {ym, y, yp};
#pragma unroll
    for (int dy = 0; dy < 3; ++dy) {
      const float* r = Sp + (size_t)rows[dy] * 256;
      float4 a = *(const float4*)(r + cs);     // 16B-aligned, 1KB/wave contiguous
      win[dy][0] = r[cl]; win[dy][1] = a.x; win[dy][2] = a.y;
      win[dy][3] = a.z;   win[dy][4] = a.w; win[dy][5] = r[cr];
    }
  }

  float* ob = out + (((size_t)(b * 64 + g * 8) * 256 + y) * 256 + cs);

#pragma unroll
  for (int oc = 0; oc < 8; ++oc) {
    const float* w = &wl[oc * 12];         // 16B-aligned: b128 + b128 + b32
    const float w00 = w[0], w01 = w[1], w02 = w[2];
    const float w10 = w[3], w11 = w[4], w12 = w[5];
    const float w20 = w[6], w21 = w[7], w22 = w[8];
    float4 o;
    o.x = w00 * win[0][0] + w01 * win[0][1] + w02 * win[0][2]
        + w10 * win[1][0] + w11 * win[1][1] + w12 * win[1][2]
        + w20 * win[2][0] + w21 * win[2][1] + w22 * win[2][2];
    o.y = w00 * win[0][1] + w01 * win[0][2] + w02 * win[0][3]
        + w10 * win[1][1] + w11 * win[1][2] + w12 * win[1][3]
        + w20 * win[2][1] + w21 * win[2][2] + w22 * win[2][3];
    o.z = w00 * win[0][2] + w01 * win[0][3] + w02 * win[0][4]
        + w10 * win[1][2] + w11 * win[1][3] + w12 * win[1][4]
        + w20 * win[2][2] + w21 * win[2][3] + w22 * win[2][4];
    o.w = w00 * win[0][3] + w01 * win[0][4] + w02 * win[0][5]
        + w10 * win[1][3] + w11 * win[1][4] + w12 * win[1][5]
        + w20 * win[2][3] + w21 * win[2][4] + w22 * win[2][5];
    *(float4*)(ob + (size_t)oc * 65536) = o;
  }
}

// ---------------- Fallback: R6 fused full-width kernel (verified) ----------
#define LROW 260
#define FTH 8
__global__ __launch_bounds__(256) void dynconv_rows(
    const float* __restrict__ x, const float* __restrict__ rep,
    const float* __restrict__ W, float* __restrict__ out) {
  const int tid = threadIdx.x;
  const int ty = blockIdx.x & 31;
  const int g  = (blockIdx.x >> 5) & 7;
  const int b  = blockIdx.x >> 8;

  __shared__ float s[(FTH + 2) * LROW];
  __shared__ float wl[96];

  if (tid < 72) {
    const int oc  = tid / 9;
    const int tap = tid - oc * 9;
    const int row = g * 72 + tid;
    const float* wr = W + (size_t)row * 32;
    const float* rb = rep + b * 32;
    float acc = 0.f;
#pragma unroll
    for (int j = 0; j < 32; ++j) acc += rb[j] * wr[j];
    wl[oc * 12 + tap] = (acc > 0.f) ? acc : 0.1f * acc;
  }

  const int gy0 = ty * FTH;
  const float* xg = x + ((size_t)(b * 64 + g * 8)) * 65536;
  const float4* xg4 = (const float4*)xg;

#pragma unroll
  for (int it = 0; it < 3; ++it) {
    const int t = tid + it * 256;
    if (it < 2 || t < 640) {
      const int row = t >> 6, seg = t & 63;
      const int yy = reflect1(gy0 + row - 1, 256);
      const float4* p = xg4 + (size_t)yy * 64 + seg;
      float4 v0 = p[0 * 16384], v1 = p[1 * 16384], v2 = p[2 * 16384], v3 = p[3 * 16384];
      float4 v4 = p[4 * 16384], v5 = p[5 * 16384], v6 = p[6 * 16384], v7 = p[7 * 16384];
      float4 a;
      a.x = ((v0.x + v1.x) + (v2.x + v3.x)) + ((v4.x + v5.x) + (v6.x + v7.x));
      a.y = ((v0.y + v1.y) + (v2.y + v3.y)) + ((v4.y + v5.y) + (v6.y + v7.y));
      a.z = ((v0.z + v1.z) + (v2.z + v3.z)) + ((v4.z + v5.z) + (v6.z + v7.z));
      a.w = ((v0.w + v1.w) + (v2.w + v3.w)) + ((v4.w + v5.w) + (v6.w + v7.w));
      *(float4*)&s[row * LROW + seg * 4] = a;
    }
  }
  __syncthreads();

  const int cs = (tid & 63) * 4;
  const int r0 = tid >> 6;

#pragma unroll
  for (int it = 0; it < 2; ++it) {
    const int rr = r0 + it * 4;
    float win[3][6];
#pragma unroll
    for (int dy = 0; dy < 3; ++dy) {
      const float* row = &s[(rr + dy) * LROW];
      float4 a = *(const float4*)&row[cs];
      float  r = row[(cs == 252) ? 254 : cs + 4];
      float  l = row[(cs == 0) ? 1 : cs - 1];
      win[dy][0] = l;   win[dy][1] = a.x; win[dy][2] = a.y;
      win[dy][3] = a.z; win[dy][4] = a.w; win[dy][5] = r;
    }
    const int y = gy0 + rr;
    float* ob = out + (((size_t)(b * 64 + g * 8) * 256 + y) * 256 + cs);
#pragma unroll
    for (int oc = 0; oc < 8; ++oc) {
      const float* w = &wl[oc * 12];
      const float w00 = w[0], w01 = w[1], w02 = w[2];
      const float w10 = w[3], w11 = w[4], w12 = w[5];
      const float w20 = w[6], w21 = w[7], w22 = w[8];
      float4 o;
      o.x = w00 * win[0][0] + w01 * win[0][1] + w02 * win[0][2]
          + w10 * win[1][0] + w11 * win[1][1] + w12 * win[1][2]
          + w20 * win[2][0] + w21 * win[2][1] + w22 * win[2][2];
      o.y = w00 * win[0][1] + w01 * win[0][2] + w02 * win[0][3]
          + w10 * win[1][1] + w11 * win[1][2] + w12 * win[1][3]
          + w20 * win[2][1] + w21 * win[2][2] + w22 * win[2][3];
      o.z = w00 * win[0][2] + w01 * win[0][3] + w02 * win[0][4]
          + w10 * win[1][2] + w11 * win[1][3] + w12 * win[1][4]
          + w20 * win[2][2] + w21 * win[2][3] + w22 * win[2][4];
      o.w = w00 * win[0][3] + w01 * win[0][4] + w02 * win[0][5]
          + w10 * win[1][3] + w11 * win[1][4] + w12 * win[1][5]
          + w20 * win[2][3] + w21 * win[2][4] + w22 * win[2][5];
      *(float4*)(ob + (size_t)oc * 65536) = o;
    }
  }
}

extern "C" void kernel_launch(void* const* d_in, const int* in_sizes, int n_in,
                              void* d_out, int out_size, void* d_ws, size_t ws_size,
                              hipStream_t stream) {
  const float* x   = (const float*)d_in[0];
  const float* rep = (const float*)d_in[1];
  const float* W   = (const float*)d_in[2];
  float* out = (float*)d_out;

  const size_t s_bytes = (size_t)8 * 8 * 256 * 256 * sizeof(float);  // 16.78 MB
  if (ws_size >= s_bytes) {
    float* S = (float*)d_ws;
    hipLaunchKernelGGL(gsum_kernel, dim3(4096), dim3(256), 0, stream, x, S);
    hipLaunchKernelGGL(conv_rows, dim3(4096), dim3(256), 0, stream,
                       S, rep, W, out);
  } else {
    hipLaunchKernelGGL(dynconv_rows, dim3(2048), dim3(256), 0, stream,
                       x, rep, W, out);
  }
}